// Round 2
// baseline (955.245 us; speedup 1.0000x reference)
//
#include <hip/hip_runtime.h>

// ---------------------------------------------------------------------------
// EnterpriseGNN: 3-layer GCN on MI355X.
//   h1 = relu(GCNConv(x, W1, b1));  h2 = relu(GCNConv(h1, W2, b2));
//   out = h2 @ Wout + bout
// GCNConv(x,W,b)[i] = dinv[i] * ( sum_{e:dst=i} w_e * g[src_e] + g[i] ) + b
//   where g = dinv .* (x@W),  dinv = rsqrt(deg+1), deg = sum_{e:dst=i} w_e.
//
// R1: scatter-atomic edge aggregation was the bottleneck (WRITE_SIZE = 400 MB
// = 1 HBM write per atomic; VALUBusy 8.5%). Replaced with per-call CSR build
// (hist -> block-scan -> cursor scatter, ~6.4M atomics total vs 153M) and
// register-accumulating pull kernels with a single store per (node,feature).
// dinv/bias/relu folded into the pull epilogue.
// ---------------------------------------------------------------------------

#define BLK 256

// --- CSR build -------------------------------------------------------------

__global__ void hist_kernel(const int* __restrict__ dst,
                            const float* __restrict__ w,
                            int* __restrict__ cnt,
                            float* __restrict__ deg, int E) {
    int e = blockIdx.x * blockDim.x + threadIdx.x;
    if (e < E) {
        int d = dst[e];
        atomicAdd(&cnt[d], 1);
        atomicAdd(&deg[d], w[e]);
    }
}

__global__ void dinv_kernel(float* __restrict__ deg, int N) {
    int i = blockIdx.x * blockDim.x + threadIdx.x;
    if (i < N) deg[i] = rsqrtf(deg[i] + 1.0f);  // in-place deg -> dinv
}

// exclusive scan of cnt within each 256-block -> rowptr (partial); block totals
__global__ void scan1_kernel(const int* __restrict__ cnt,
                             int* __restrict__ rowptr,
                             int* __restrict__ bsums, int N) {
    __shared__ int tmp[BLK];
    int i = blockIdx.x * BLK + threadIdx.x;
    int v = (i < N) ? cnt[i] : 0;
    tmp[threadIdx.x] = v;
    __syncthreads();
    for (int off = 1; off < BLK; off <<= 1) {
        int t = (threadIdx.x >= off) ? tmp[threadIdx.x - off] : 0;
        __syncthreads();
        tmp[threadIdx.x] += t;
        __syncthreads();
    }
    if (i < N) rowptr[i] = tmp[threadIdx.x] - v;       // exclusive
    if (threadIdx.x == BLK - 1) bsums[blockIdx.x] = tmp[BLK - 1];
}

// exclusive scan of block sums (single block, M <= 1024)
__global__ void scan2_kernel(int* __restrict__ bsums, int M) {
    __shared__ int tmp[1024];
    int v = (threadIdx.x < M) ? bsums[threadIdx.x] : 0;
    tmp[threadIdx.x] = v;
    __syncthreads();
    for (int off = 1; off < 1024; off <<= 1) {
        int t = (threadIdx.x >= off) ? tmp[threadIdx.x - off] : 0;
        __syncthreads();
        tmp[threadIdx.x] += t;
        __syncthreads();
    }
    if (threadIdx.x < M) bsums[threadIdx.x] = tmp[threadIdx.x] - v;
}

__global__ void scan3_kernel(int* __restrict__ rowptr,
                             int* __restrict__ cursor,
                             const int* __restrict__ bsums, int N, int E) {
    int i = blockIdx.x * BLK + threadIdx.x;
    if (i < N) {
        int r = rowptr[i] + bsums[blockIdx.x];
        rowptr[i] = r;
        cursor[i] = r;
    }
    if (i == 0) rowptr[N] = E;
}

__global__ void scatter_kernel(const int* __restrict__ src,
                               const int* __restrict__ dst,
                               const float* __restrict__ w,
                               int* __restrict__ cursor,
                               uint2* __restrict__ csr, int E) {
    int e = blockIdx.x * blockDim.x + threadIdx.x;
    if (e < E) {
        int d = dst[e];
        int pos = atomicAdd(&cursor[d], 1);
        csr[pos] = make_uint2((unsigned)src[e], __float_as_uint(w[e]));
    }
}

// --- dense layers ----------------------------------------------------------

// g1[i][j] = dinv[i] * sum_k x[i][k] * W1[k][j]   (128 -> 32)
__global__ void gemm1_kernel(const float* __restrict__ x,
                             const float* __restrict__ W1,
                             const float* __restrict__ dinv,
                             float* __restrict__ g1, int N) {
    __shared__ float sW[128 * 32];   // 16 KB
    __shared__ float sx[8][128];     // 4 KB
    for (int i = threadIdx.x; i < 128 * 32; i += BLK) sW[i] = W1[i];
    int node0 = blockIdx.x * 8;
    for (int i = threadIdx.x; i < 8 * 128; i += BLK) {
        int r = i >> 7, c = i & 127;
        int n = node0 + r;
        sx[r][c] = (n < N) ? x[(long long)n * 128 + c] : 0.f;
    }
    __syncthreads();
    int local = threadIdx.x >> 5;     // node within block (0..7)
    int j = threadIdx.x & 31;         // output feature
    int n = node0 + local;
    if (n < N) {
        float acc = 0.f;
#pragma unroll 16
        for (int k = 0; k < 128; k++) acc += sx[local][k] * sW[k * 32 + j];
        g1[n * 32 + j] = acc * dinv[n];
    }
}

// g2 = dinv .* (h1 @ W2)   (32 -> 16)
__global__ void gemm2_kernel(const float* __restrict__ h1,
                             const float* __restrict__ dinv,
                             const float* __restrict__ W2,
                             float* __restrict__ g2, int N) {
    __shared__ float sW[32 * 16];
    __shared__ float sin_[16][32];
    for (int i = threadIdx.x; i < 32 * 16; i += BLK) sW[i] = W2[i];
    int node0 = blockIdx.x * 16;
    for (int i = threadIdx.x; i < 16 * 32; i += BLK) {
        int r = i >> 5, c = i & 31;
        int n = node0 + r;
        sin_[r][c] = (n < N) ? h1[n * 32 + c] : 0.f;
    }
    __syncthreads();
    int local = threadIdx.x >> 4;   // 0..15
    int j = threadIdx.x & 15;
    int n = node0 + local;
    if (n < N) {
        float acc = 0.f;
#pragma unroll
        for (int k = 0; k < 32; k++) acc += sin_[local][k] * sW[k * 16 + j];
        g2[n * 16 + j] = acc * dinv[n];
    }
}

// h[n][f] = relu( dinv[n] * ( g[n][f] + sum_{e: dst=n} w_e * g[src_e][f] ) + b[f] )
template <int F>
__global__ void pull_kernel(const int* __restrict__ rowptr,
                            const uint2* __restrict__ csr,
                            const float* __restrict__ g,
                            const float* __restrict__ dinv,
                            const float* __restrict__ b,
                            float* __restrict__ h, int N) {
    unsigned idx = blockIdx.x * BLK + threadIdx.x;
    unsigned n = idx / F;
    unsigned f = idx & (F - 1);
    if (n >= (unsigned)N) return;
    int r0 = rowptr[n], r1 = rowptr[n + 1];
    float acc = g[n * F + f];                      // self-loop (weight 1)
    for (int i = r0; i < r1; i++) {
        uint2 e = csr[i];
        acc += __uint_as_float(e.y) * g[(size_t)e.x * F + f];
    }
    h[n * F + f] = fmaxf(dinv[n] * acc + b[f], 0.f);
}

// out = h2 @ Wout + bout   (16 -> 3)
__global__ void final_kernel(const float* __restrict__ h2,
                             const float* __restrict__ Wout,
                             const float* __restrict__ bout,
                             float* __restrict__ out, int N) {
    int n = blockIdx.x * blockDim.x + threadIdx.x;
    if (n >= N) return;
    float o0 = bout[0], o1 = bout[1], o2 = bout[2];
#pragma unroll
    for (int k = 0; k < 16; k++) {
        float v = h2[n * 16 + k];
        o0 += v * Wout[k * 3 + 0];
        o1 += v * Wout[k * 3 + 1];
        o2 += v * Wout[k * 3 + 2];
    }
    out[n * 3 + 0] = o0;
    out[n * 3 + 1] = o1;
    out[n * 3 + 2] = o2;
}

extern "C" void kernel_launch(void* const* d_in, const int* in_sizes, int n_in,
                              void* d_out, int out_size, void* d_ws, size_t ws_size,
                              hipStream_t stream) {
    const float* x    = (const float*)d_in[0];
    const int* ei     = (const int*)d_in[1];   // [2, E]: row0 = src, row1 = dst
    const float* ew   = (const float*)d_in[2];
    const float* W1   = (const float*)d_in[3];
    const float* b1   = (const float*)d_in[4];
    const float* W2   = (const float*)d_in[5];
    const float* b2   = (const float*)d_in[6];
    const float* Wout = (const float*)d_in[7];
    const float* bout = (const float*)d_in[8];
    float* out = (float*)d_out;

    const int N = in_sizes[0] / 128;
    const int E = in_sizes[2];
    const int* src = ei;
    const int* dst = ei + E;
    const int NB = (N + BLK - 1) / BLK;   // scan blocks (391 for N=100K)

    // workspace layout (4-byte units from base):
    //  deg/dinv: N | cnt: N | rowptr: N+1 | cursor: N | bsums: 1024 | pad
    //  csr: E uint2 (8B-aligned) | g1: 32N | h1: 32N | g2: 16N
    //  h2 aliases g1 (g1 dead after pull<32>)
    float* ws   = (float*)d_ws;
    float* deg  = ws;                             // -> dinv in place
    int* cnt    = (int*)(ws + N);
    int* rowptr = cnt + N;
    int* cursor = rowptr + N + 1;
    int* bsums  = cursor + N;
    size_t off  = (size_t)4 * N + 1 + 1024;
    off = (off + 1) & ~(size_t)1;                 // 8B align for uint2
    uint2* csr  = (uint2*)(ws + off);
    float* g1   = (float*)(csr + E);
    float* h1   = g1 + (size_t)32 * N;
    float* g2   = h1 + (size_t)32 * N;
    float* h2   = g1;                             // alias: g1 dead after pull<32>

    // zero deg + cnt (contiguous 2N words); everything else fully overwritten
    hipMemsetAsync(ws, 0, (size_t)2 * N * sizeof(float), stream);

    hist_kernel<<<(E + BLK - 1) / BLK, BLK, 0, stream>>>(dst, ew, cnt, deg, E);
    dinv_kernel<<<NB, BLK, 0, stream>>>(deg, N);

    scan1_kernel<<<NB, BLK, 0, stream>>>(cnt, rowptr, bsums, N);
    scan2_kernel<<<1, 1024, 0, stream>>>(bsums, NB);
    scan3_kernel<<<NB, BLK, 0, stream>>>(rowptr, cursor, bsums, N, E);
    scatter_kernel<<<(E + BLK - 1) / BLK, BLK, 0, stream>>>(src, dst, ew, cursor, csr, E);

    gemm1_kernel<<<(N + 7) / 8, BLK, 0, stream>>>(x, W1, deg, g1, N);

    pull_kernel<32><<<((unsigned)N * 32 + BLK - 1) / BLK, BLK, 0, stream>>>(
        rowptr, csr, g1, deg, b1, h1, N);

    gemm2_kernel<<<(N + 15) / 16, BLK, 0, stream>>>(h1, deg, W2, g2, N);

    pull_kernel<16><<<((unsigned)N * 16 + BLK - 1) / BLK, BLK, 0, stream>>>(
        rowptr, csr, g2, deg, b2, h2, N);

    final_kernel<<<NB, BLK, 0, stream>>>(h2, Wout, bout, out, N);
}